// Round 1
// baseline (282.379 us; speedup 1.0000x reference)
//
#include <hip/hip_runtime.h>
#include <hip/hip_bf16.h>

typedef short bf16x4 __attribute__((ext_vector_type(4)));
typedef short bf16x8 __attribute__((ext_vector_type(8)));
typedef float f32x4  __attribute__((ext_vector_type(4)));

#define LOG2E 1.4426950408889634f
#define QSCALE (0.125f * LOG2E)   // 1/sqrt(64) * log2(e), folded into Q

__device__ __forceinline__ short f2bf(float x) {
  union { __hip_bfloat16 h; short s; } u;
  u.h = __float2bfloat16(x);
  return u.s;
}

// global -> LDS direct copy, 16B per lane. LDS dest = uniform base + lane*16.
__device__ __forceinline__ void load16_lds(const short* g, short* l) {
#if __has_builtin(__builtin_amdgcn_global_load_lds)
  __builtin_amdgcn_global_load_lds(
      (const __attribute__((address_space(1))) unsigned int*)g,
      (__attribute__((address_space(3))) unsigned int*)l, 16, 0, 0);
#else
  const int lane = threadIdx.x & 63;
  *(bf16x8*)((char*)l + lane * 16) = *(const bf16x8*)g;
#endif
}

__device__ __forceinline__ f32x4 mfma16x16x16_bf16(bf16x4 a, bf16x4 b, f32x4 c) {
#if __has_builtin(__builtin_amdgcn_mfma_f32_16x16x16bf16_1k)
  return __builtin_amdgcn_mfma_f32_16x16x16bf16_1k(a, b, c, 0, 0, 0);
#else
  asm volatile("v_mfma_f32_16x16x16_bf16 %0, %1, %2, %0" : "+v"(c) : "v"(a), "v"(b));
  return c;
#endif
}

// ---------------------------------------------------------------- gate scale
__global__ void gate_kernel(const float* __restrict__ gate, float* __restrict__ scale) {
  const int h = threadIdx.x;
  if (h >= 16) return;
  const float g = gate[h];
  const float eff = (g >= 1e-4f) ? g : 0.f;
  int active = 0;
  for (int j = 0; j < 16; ++j) active += (gate[j] > 1e-4f) ? 1 : 0;
  const float denom = fmaxf(1.f, (float)active / 16.f);
  scale[h] = eff / denom;
}

// ---------------------------------------------------------------- x -> bf16
__global__ __launch_bounds__(256)
void cvt_x_kernel(const float* __restrict__ in, short* __restrict__ out, int n4) {
  for (int i = blockIdx.x * blockDim.x + threadIdx.x; i < n4; i += gridDim.x * blockDim.x) {
    const float4 v = ((const float4*)in)[i];
    bf16x4 o;
    o[0] = f2bf(v.x); o[1] = f2bf(v.y); o[2] = f2bf(v.z); o[3] = f2bf(v.w);
    ((bf16x4*)out)[i] = o;
  }
}

// ------------------------------------------- [R][C] f32 -> [C][R] bf16 (per z-slice)
__global__ __launch_bounds__(256)
void transpose_conv_kernel(const float* __restrict__ in, short* __restrict__ out,
                           int R, int C, int inStride, int outStride) {
  __shared__ float t[32][33];
  const float* ip = in + (size_t)blockIdx.z * inStride;
  short* op = out + (size_t)blockIdx.z * outStride;
  const int r0 = blockIdx.x * 32, c0 = blockIdx.y * 32;
  const int tr = threadIdx.x >> 5, tc = threadIdx.x & 31;
#pragma unroll
  for (int p = 0; p < 4; ++p)
    t[tr + p * 8][tc] = ip[(size_t)(r0 + tr + p * 8) * C + c0 + tc];
  __syncthreads();
#pragma unroll
  for (int p = 0; p < 4; ++p)
    op[(size_t)(c0 + tr + p * 8) * R + r0 + tc] = f2bf(t[tc][tr + p * 8]);
}

// ---------------------------------------------------------------- GEMM (m97 recipe)
// C[M][N] = A[M][K=1024] * Bt[N][K=1024]^T, 128x128 tile, BK=32, 4 waves.
// MODE 0: out bf16 Q[B,H,S,D] * QSCALE   MODE 1: out bf16 K[B,H,S,D]
// MODE 2: out bf16 Vt[B,H,D,S]           MODE 3: out f32 [M][N]
template <int MODE>
__global__ __launch_bounds__(256)
void gemm_bt_kernel(const short* __restrict__ A, const short* __restrict__ Bt,
                    void* __restrict__ OutP) {
  __shared__ short Al[128 * 32];
  __shared__ short Bl[128 * 32];
  const int tid = threadIdx.x;
  const int w = tid >> 6, lane = tid & 63;
  const int lq = lane & 15, lg = lane >> 4;
  const int m0 = blockIdx.x * 128, n0 = blockIdx.y * 128;
  const int wr = (w >> 1) * 64, wc = (w & 1) * 64;

  f32x4 acc[4][4] = {};
  const int grow = lane >> 2;       // row within 16-row chunk (64B rows)
  const int gcol = (lane & 3) * 8;  // 8-short col offset

  for (int k0 = 0; k0 < 1024; k0 += 32) {
#pragma unroll
    for (int c = 0; c < 2; ++c) {
      const int chunk = (w << 1) | c;   // 0..7, wave-uniform
      const int row = chunk * 16 + grow;
      load16_lds(A + (size_t)(m0 + row) * 1024 + k0 + gcol, &Al[chunk * 512]);
      load16_lds(Bt + (size_t)(n0 + row) * 1024 + k0 + gcol, &Bl[chunk * 512]);
    }
    __syncthreads();
    bf16x8 af[4], bfr[4];
#pragma unroll
    for (int i = 0; i < 4; ++i)
      af[i] = *(const bf16x8*)&Al[(wr + i * 16 + lq) * 32 + lg * 8];
#pragma unroll
    for (int j = 0; j < 4; ++j)
      bfr[j] = *(const bf16x8*)&Bl[(wc + j * 16 + lq) * 32 + lg * 8];
#pragma unroll
    for (int i = 0; i < 4; ++i)
#pragma unroll
      for (int j = 0; j < 4; ++j)
        acc[i][j] = __builtin_amdgcn_mfma_f32_16x16x32_bf16(af[i], bfr[j], acc[i][j], 0, 0, 0);
    __syncthreads();
  }

  if (MODE == 0 || MODE == 1) {
    short* Out = (short*)OutP;
#pragma unroll
    for (int i = 0; i < 4; ++i)
#pragma unroll
      for (int j = 0; j < 4; ++j) {
        const int n = n0 + wc + j * 16 + lq;
        const int h = n >> 6, d = n & 63;
#pragma unroll
        for (int r = 0; r < 4; ++r) {
          const int m = m0 + wr + i * 16 + lg * 4 + r;
          const int b = m >> 11, s = m & 2047;
          float v = acc[i][j][r];
          if (MODE == 0) v *= QSCALE;
          Out[(size_t)((b * 16 + h) * 2048 + s) * 64 + d] = f2bf(v);
        }
      }
  } else if (MODE == 2) {
    short* Out = (short*)OutP;
#pragma unroll
    for (int i = 0; i < 4; ++i) {
      const int mb = m0 + wr + i * 16 + lg * 4;  // 4 consecutive s, same b
      const int b = mb >> 11, s = mb & 2047;
#pragma unroll
      for (int j = 0; j < 4; ++j) {
        const int n = n0 + wc + j * 16 + lq;
        const int h = n >> 6, d = n & 63;
        bf16x4 o;
#pragma unroll
        for (int r = 0; r < 4; ++r) o[r] = f2bf(acc[i][j][r]);
        *(bf16x4*)&Out[(size_t)((b * 16 + h) * 64 + d) * 2048 + s] = o;
      }
    }
  } else {
    float* Out = (float*)OutP;
#pragma unroll
    for (int i = 0; i < 4; ++i)
#pragma unroll
      for (int r = 0; r < 4; ++r) {
        const int m = m0 + wr + i * 16 + lg * 4 + r;
        float* orow = Out + (size_t)m * 1024 + n0 + wc;
#pragma unroll
        for (int j = 0; j < 4; ++j) orow[j * 16 + lq] = acc[i][j][r];
      }
  }
}

// ---------------------------------------------------------------- flash attention
// grid: x = q-tile (64 rows), y = b*16+h. 4 waves x 16 q-rows each.
// Scores: S^T[key][q] = mfma_16x16x32(K_frag, Q_frag). S^T C/D layout feeds the
// PV mfma_16x16x16 B operand directly (register-exact match, no relayout).
__global__ __launch_bounds__(256)
void attn_kernel(const short* __restrict__ Qb, const short* __restrict__ Kb,
                 const short* __restrict__ Vt, const float* __restrict__ mask,
                 const float* __restrict__ gscale, short* __restrict__ ctx) {
  __shared__ short Kl[64 * 72];  // [key][d], pad 8 -> 2-way-conflict-free b128 reads
  __shared__ short Vl[64 * 72];  // [d][key]
  __shared__ float Ml[64];

  const int tid = threadIdx.x;
  const int w = tid >> 6, lane = tid & 63;
  const int lq = lane & 15, lg = lane >> 4;
  const int bh = blockIdx.y, b = bh >> 4, h = bh & 15;
  const int q0 = blockIdx.x * 64;
  const size_t bhoff = (size_t)bh * 2048 * 64;

  const int qrow = q0 + w * 16 + lq;
  const bf16x8 qf0 = *(const bf16x8*)(Qb + bhoff + (size_t)qrow * 64 + lg * 8);
  const bf16x8 qf1 = *(const bf16x8*)(Qb + bhoff + (size_t)qrow * 64 + 32 + lg * 8);

  f32x4 acc_o[4] = {};  // O^T[d = dt*16 + lg*4 + r][q = lq]
  float m_run = -1e30f, l_run = 0.f;

  for (int kt0 = 0; kt0 < 2048; kt0 += 64) {
#pragma unroll
    for (int rnd = 0; rnd < 2; ++rnd) {
      const int i = tid + rnd * 256;
      const int r = i >> 3, c = (i & 7) * 8;
      *(bf16x8*)&Kl[r * 72 + c] = *(const bf16x8*)(Kb + bhoff + (size_t)(kt0 + r) * 64 + c);
      *(bf16x8*)&Vl[r * 72 + c] = *(const bf16x8*)(Vt + bhoff + (size_t)r * 2048 + kt0 + c);
    }
    if (tid < 64) Ml[tid] = mask[b * 2048 + kt0 + tid] * LOG2E;
    __syncthreads();

    // scores: 4 key-tiles x (K=64 via 2 mfma)
    f32x4 s[4];
#pragma unroll
    for (int kt = 0; kt < 4; ++kt) {
      const bf16x8 ka0 = *(const bf16x8*)&Kl[(kt * 16 + lq) * 72 + lg * 8];
      const bf16x8 ka1 = *(const bf16x8*)&Kl[(kt * 16 + lq) * 72 + 32 + lg * 8];
      f32x4 t = {};
      t = __builtin_amdgcn_mfma_f32_16x16x32_bf16(ka0, qf0, t, 0, 0, 0);
      t = __builtin_amdgcn_mfma_f32_16x16x32_bf16(ka1, qf1, t, 0, 0, 0);
      s[kt] = t;
    }
    // mask add + tile max
    float pm = -1e30f;
#pragma unroll
    for (int kt = 0; kt < 4; ++kt) {
      const f32x4 mv = *(const f32x4*)&Ml[kt * 16 + lg * 4];
      s[kt] += mv;
      pm = fmaxf(pm, fmaxf(fmaxf(s[kt][0], s[kt][1]), fmaxf(s[kt][2], s[kt][3])));
    }
    pm = fmaxf(pm, __shfl_xor(pm, 16));
    pm = fmaxf(pm, __shfl_xor(pm, 32));
    const float m_new = fmaxf(m_run, pm);
    const float resc = exp2f(m_run - m_new);

    float psum = 0.f;
    bf16x4 pf[4];
#pragma unroll
    for (int kt = 0; kt < 4; ++kt) {
#pragma unroll
      for (int r = 0; r < 4; ++r) {
        const float p = exp2f(s[kt][r] - m_new);
        psum += p;
        pf[kt][r] = f2bf(p);
      }
    }
    psum += __shfl_xor(psum, 16);
    psum += __shfl_xor(psum, 32);
    l_run = l_run * resc + psum;
    m_run = m_new;

#pragma unroll
    for (int dt = 0; dt < 4; ++dt) {
      acc_o[dt][0] *= resc; acc_o[dt][1] *= resc;
      acc_o[dt][2] *= resc; acc_o[dt][3] *= resc;
    }
    // PV: O^T[d][q] += V^T_frag * P^T_frag (P straight from score registers)
#pragma unroll
    for (int dt = 0; dt < 4; ++dt) {
      const short* vrow = &Vl[(dt * 16 + lq) * 72];
#pragma unroll
      for (int kt = 0; kt < 4; ++kt) {
        const bf16x4 vf = *(const bf16x4*)(vrow + kt * 16 + lg * 4);
        acc_o[dt] = mfma16x16x16_bf16(vf, pf[kt], acc_o[dt]);
      }
    }
    __syncthreads();
  }

  const float inv = gscale[h] / l_run;
#pragma unroll
  for (int dt = 0; dt < 4; ++dt) {
    bf16x4 o;
#pragma unroll
    for (int r = 0; r < 4; ++r) o[r] = f2bf(acc_o[dt][r] * inv);
    *(bf16x4*)&ctx[(size_t)(b * 2048 + qrow) * 1024 + h * 64 + dt * 16 + lg * 4] = o;
  }
}

// ---------------------------------------------------------------- launch
extern "C" void kernel_launch(void* const* d_in, const int* in_sizes, int n_in,
                              void* d_out, int out_size, void* d_ws, size_t ws_size,
                              hipStream_t stream) {
  (void)in_sizes; (void)n_in; (void)out_size; (void)ws_size;
  const float* x    = (const float*)d_in[0];
  const float* mask = (const float*)d_in[1];
  const float* Wq   = (const float*)d_in[2];
  const float* Wk   = (const float*)d_in[3];
  const float* Wv   = (const float*)d_in[4];
  const float* Wo   = (const float*)d_in[5];
  const float* gate = (const float*)d_in[6];
  float* out = (float*)d_out;

  char* ws = (char*)d_ws;
  const size_t MB = 1024 * 1024;
  float* scale = (float*)ws;
  short* Xb  = (short*)(ws + 256);             // 8 MB  [4096][1024]
  short* Wtq = (short*)(ws + 256 + 8 * MB);    // 2 MB  [hd][e] per-head-transposed
  short* Wtk = (short*)(ws + 256 + 10 * MB);
  short* Wtv = (short*)(ws + 256 + 12 * MB);
  short* Wot = (short*)(ws + 256 + 14 * MB);   // 2 MB  [e][hd]
  short* Qb  = (short*)(ws + 256 + 16 * MB);   // 8 MB  [B,H,S,D] (pre-scaled)
  short* Kb  = (short*)(ws + 256 + 24 * MB);   // 8 MB  [B,H,S,D]
  short* Vt  = (short*)(ws + 256 + 32 * MB);   // 8 MB  [B,H,D,S]
  short* ctx = (short*)(ws + 256 + 40 * MB);   // 8 MB  [4096][1024] gate-scaled

  gate_kernel<<<1, 64, 0, stream>>>(gate, scale);
  cvt_x_kernel<<<2048, 256, 0, stream>>>(x, Xb, 4194304 / 4);
  transpose_conv_kernel<<<dim3(32, 2, 16), 256, 0, stream>>>(Wq, Wtq, 1024, 64, 65536, 65536);
  transpose_conv_kernel<<<dim3(32, 2, 16), 256, 0, stream>>>(Wk, Wtk, 1024, 64, 65536, 65536);
  transpose_conv_kernel<<<dim3(32, 2, 16), 256, 0, stream>>>(Wv, Wtv, 1024, 64, 65536, 65536);
  transpose_conv_kernel<<<dim3(32, 32, 1), 256, 0, stream>>>(Wo, Wot, 1024, 1024, 0, 0);
  gemm_bt_kernel<0><<<dim3(32, 8), 256, 0, stream>>>(Xb, Wtq, Qb);
  gemm_bt_kernel<1><<<dim3(32, 8), 256, 0, stream>>>(Xb, Wtk, Kb);
  gemm_bt_kernel<2><<<dim3(32, 8), 256, 0, stream>>>(Xb, Wtv, Vt);
  attn_kernel<<<dim3(32, 32), 256, 0, stream>>>(Qb, Kb, Vt, mask, scale, ctx);
  gemm_bt_kernel<3><<<dim3(32, 8), 256, 0, stream>>>(ctx, Wot, out);
}

// Round 2
// 234.418 us; speedup vs baseline: 1.2046x; 1.2046x over previous
//
#include <hip/hip_runtime.h>
#include <hip/hip_bf16.h>

typedef short bf16x4 __attribute__((ext_vector_type(4)));
typedef short bf16x8 __attribute__((ext_vector_type(8)));
typedef float f32x4  __attribute__((ext_vector_type(4)));

#define LOG2E 1.4426950408889634f
#define QSCALE (0.125f * LOG2E)   // 1/sqrt(64) * log2(e), folded into Q

__device__ __forceinline__ short f2bf(float x) {
  union { __hip_bfloat16 h; short s; } u;
  u.h = __float2bfloat16(x);
  return u.s;
}

// global -> LDS direct copy, 16B per lane. LDS dest = uniform base + lane*16.
__device__ __forceinline__ void load16_lds(const short* g, short* l) {
#if __has_builtin(__builtin_amdgcn_global_load_lds)
  __builtin_amdgcn_global_load_lds(
      (const __attribute__((address_space(1))) unsigned int*)g,
      (__attribute__((address_space(3))) unsigned int*)l, 16, 0, 0);
#else
  const int lane = threadIdx.x & 63;
  *(bf16x8*)((char*)l + lane * 16) = *(const bf16x8*)g;
#endif
}

// ---------------------------------------------------------------- gate scale
__global__ void gate_kernel(const float* __restrict__ gate, float* __restrict__ scale) {
  const int h = threadIdx.x;
  if (h >= 16) return;
  const float g = gate[h];
  const float eff = (g >= 1e-4f) ? g : 0.f;
  int active = 0;
  for (int j = 0; j < 16; ++j) active += (gate[j] > 1e-4f) ? 1 : 0;
  const float denom = fmaxf(1.f, (float)active / 16.f);
  scale[h] = eff / denom;
}

// ---------------------------------------------------------------- x -> bf16
__global__ __launch_bounds__(256)
void cvt_x_kernel(const float* __restrict__ in, short* __restrict__ out, int n4) {
  for (int i = blockIdx.x * blockDim.x + threadIdx.x; i < n4; i += gridDim.x * blockDim.x) {
    const float4 v = ((const float4*)in)[i];
    bf16x4 o;
    o[0] = f2bf(v.x); o[1] = f2bf(v.y); o[2] = f2bf(v.z); o[3] = f2bf(v.w);
    ((bf16x4*)out)[i] = o;
  }
}

// ------------------------------------------- [R][C] f32 -> [C][R] bf16 (per z-slice)
__global__ __launch_bounds__(256)
void transpose_conv_kernel(const float* __restrict__ in, short* __restrict__ out,
                           int R, int C, int inStride, int outStride) {
  __shared__ float t[32][33];
  const float* ip = in + (size_t)blockIdx.z * inStride;
  short* op = out + (size_t)blockIdx.z * outStride;
  const int r0 = blockIdx.x * 32, c0 = blockIdx.y * 32;
  const int tr = threadIdx.x >> 5, tc = threadIdx.x & 31;
#pragma unroll
  for (int p = 0; p < 4; ++p)
    t[tr + p * 8][tc] = ip[(size_t)(r0 + tr + p * 8) * C + c0 + tc];
  __syncthreads();
#pragma unroll
  for (int p = 0; p < 4; ++p)
    op[(size_t)(c0 + tr + p * 8) * R + r0 + tc] = f2bf(t[tc][tr + p * 8]);
}

// ---------------------------------------------------------------- fused QKV GEMM
// C[4096][3072] = Xb[4096][1024] * Wt3[3072][1024]^T; 128x128 tile, 4 waves.
// n0 in [0,1024): Q (scaled) -> Qb[B,H,S,D]; [1024,2048): K -> Kb; [2048,3072): Vt[B,H,D,S].
__global__ __launch_bounds__(256)
void gemm_qkv_kernel(const short* __restrict__ A, const short* __restrict__ Bt,
                     short* __restrict__ Qb, short* __restrict__ Kb,
                     short* __restrict__ Vt) {
  __shared__ short Al[128 * 32];
  __shared__ short Bl[128 * 32];
  const int tid = threadIdx.x;
  const int w = tid >> 6, lane = tid & 63;
  const int lq = lane & 15, lg = lane >> 4;
  const int m0 = blockIdx.x * 128, n0 = blockIdx.y * 128;
  const int which = n0 >> 10;  // 0=Q 1=K 2=V, uniform per block
  const int wr = (w >> 1) * 64, wc = (w & 1) * 64;

  f32x4 acc[4][4] = {};
  const int grow = lane >> 2;
  const int gcol = (lane & 3) * 8;

  for (int k0 = 0; k0 < 1024; k0 += 32) {
#pragma unroll
    for (int c = 0; c < 2; ++c) {
      const int chunk = (w << 1) | c;
      const int row = chunk * 16 + grow;
      load16_lds(A + (size_t)(m0 + row) * 1024 + k0 + gcol, &Al[chunk * 512]);
      load16_lds(Bt + (size_t)(n0 + row) * 1024 + k0 + gcol, &Bl[chunk * 512]);
    }
    __syncthreads();
    bf16x8 af[4], bfr[4];
#pragma unroll
    for (int i = 0; i < 4; ++i)
      af[i] = *(const bf16x8*)&Al[(wr + i * 16 + lq) * 32 + lg * 8];
#pragma unroll
    for (int j = 0; j < 4; ++j)
      bfr[j] = *(const bf16x8*)&Bl[(wc + j * 16 + lq) * 32 + lg * 8];
#pragma unroll
    for (int i = 0; i < 4; ++i)
#pragma unroll
      for (int j = 0; j < 4; ++j)
        acc[i][j] = __builtin_amdgcn_mfma_f32_16x16x32_bf16(af[i], bfr[j], acc[i][j], 0, 0, 0);
    __syncthreads();
  }

  if (which < 2) {
    short* Out = which ? Kb : Qb;
    const float sc = which ? 1.f : QSCALE;
#pragma unroll
    for (int i = 0; i < 4; ++i)
#pragma unroll
      for (int j = 0; j < 4; ++j) {
        const int nn = (n0 + wc + j * 16 + lq) & 1023;
        const int h = nn >> 6, d = nn & 63;
#pragma unroll
        for (int r = 0; r < 4; ++r) {
          const int m = m0 + wr + i * 16 + lg * 4 + r;
          const int b = m >> 11, s = m & 2047;
          Out[(size_t)((b * 16 + h) * 2048 + s) * 64 + d] = f2bf(acc[i][j][r] * sc);
        }
      }
  } else {
#pragma unroll
    for (int i = 0; i < 4; ++i) {
      const int mb = m0 + wr + i * 16 + lg * 4;
      const int b = mb >> 11, s = mb & 2047;
#pragma unroll
      for (int j = 0; j < 4; ++j) {
        const int nn = (n0 + wc + j * 16 + lq) & 1023;
        const int h = nn >> 6, d = nn & 63;
        bf16x4 o;
#pragma unroll
        for (int r = 0; r < 4; ++r) o[r] = f2bf(acc[i][j][r]);
        *(bf16x4*)&Vt[(size_t)((b * 16 + h) * 64 + d) * 2048 + s] = o;
      }
    }
  }
}

// ---------------------------------------------------------------- out-proj GEMM
__global__ __launch_bounds__(256)
void gemm_out_kernel(const short* __restrict__ A, const short* __restrict__ Bt,
                     float* __restrict__ Out) {
  __shared__ short Al[128 * 32];
  __shared__ short Bl[128 * 32];
  const int tid = threadIdx.x;
  const int w = tid >> 6, lane = tid & 63;
  const int lq = lane & 15, lg = lane >> 4;
  const int m0 = blockIdx.x * 128, n0 = blockIdx.y * 128;
  const int wr = (w >> 1) * 64, wc = (w & 1) * 64;

  f32x4 acc[4][4] = {};
  const int grow = lane >> 2;
  const int gcol = (lane & 3) * 8;

  for (int k0 = 0; k0 < 1024; k0 += 32) {
#pragma unroll
    for (int c = 0; c < 2; ++c) {
      const int chunk = (w << 1) | c;
      const int row = chunk * 16 + grow;
      load16_lds(A + (size_t)(m0 + row) * 1024 + k0 + gcol, &Al[chunk * 512]);
      load16_lds(Bt + (size_t)(n0 + row) * 1024 + k0 + gcol, &Bl[chunk * 512]);
    }
    __syncthreads();
    bf16x8 af[4], bfr[4];
#pragma unroll
    for (int i = 0; i < 4; ++i)
      af[i] = *(const bf16x8*)&Al[(wr + i * 16 + lq) * 32 + lg * 8];
#pragma unroll
    for (int j = 0; j < 4; ++j)
      bfr[j] = *(const bf16x8*)&Bl[(wc + j * 16 + lq) * 32 + lg * 8];
#pragma unroll
    for (int i = 0; i < 4; ++i)
#pragma unroll
      for (int j = 0; j < 4; ++j)
        acc[i][j] = __builtin_amdgcn_mfma_f32_16x16x32_bf16(af[i], bfr[j], acc[i][j], 0, 0, 0);
    __syncthreads();
  }

#pragma unroll
  for (int i = 0; i < 4; ++i)
#pragma unroll
    for (int r = 0; r < 4; ++r) {
      const int m = m0 + wr + i * 16 + lg * 4 + r;
      float* orow = Out + (size_t)m * 1024 + n0 + wc;
#pragma unroll
      for (int j = 0; j < 4; ++j) orow[j * 16 + lq] = acc[i][j][r];
    }
}

// ---------------------------------------------------------------- flash attention
// grid x=q-tile(64), y=b*16+h. 4 waves x 16 q-rows. 64-key tiles, double-buffered
// LDS (1 barrier/tile), reg-staged loads issued before compute (T14), defer-max
// rescale (T13, THR=8). Scores: S^T = mfma32(K,Q). PV at K=32 via key
// permutation: B-frag slot k=lg*8+j carries P[kappa(k)], V A-frag reads Vl at
// the same kappa(k) -> sum over keys is permutation-invariant.
__global__ __launch_bounds__(256)
void attn_kernel(const short* __restrict__ Qb, const short* __restrict__ Kb,
                 const short* __restrict__ Vt, const float* __restrict__ mask,
                 const float* __restrict__ gscale, short* __restrict__ ctx) {
  __shared__ short Kl[2][64 * 72];  // [key][d], +8 pad
  __shared__ short Vl[2][64 * 72];  // [d][key], +8 pad
  __shared__ float Ml[2][64];

  const int tid = threadIdx.x;
  const int w = tid >> 6, lane = tid & 63;
  const int lq = lane & 15, lg = lane >> 4;
  const int bh = blockIdx.y, b = bh >> 4, h = bh & 15;
  const int q0 = blockIdx.x * 64;
  const size_t bhoff = (size_t)bh * 2048 * 64;

  const int qrow = q0 + w * 16 + lq;
  const bf16x8 qf0 = *(const bf16x8*)(Qb + bhoff + (size_t)qrow * 64 + lg * 8);
  const bf16x8 qf1 = *(const bf16x8*)(Qb + bhoff + (size_t)qrow * 64 + 32 + lg * 8);

  // staging map: per rnd, 32 rows x 64 shorts; lane -> row tid>>3, col (tid&7)*8
  const int sr = tid >> 3, sc = (tid & 7) * 8;

  f32x4 acc[4] = {};  // O^T[d = dt*16 + lg*4 + r][q = lq]
  float m_run = -1e30f, l_run = 0.f;

  // prologue: stage tile 0
  {
    const bf16x8 k0 = *(const bf16x8*)(Kb + bhoff + (size_t)sr * 64 + sc);
    const bf16x8 k1 = *(const bf16x8*)(Kb + bhoff + (size_t)(32 + sr) * 64 + sc);
    const bf16x8 v0 = *(const bf16x8*)(Vt + bhoff + (size_t)sr * 2048 + sc);
    const bf16x8 v1 = *(const bf16x8*)(Vt + bhoff + (size_t)(32 + sr) * 2048 + sc);
    *(bf16x8*)&Kl[0][sr * 72 + sc] = k0;
    *(bf16x8*)&Kl[0][(32 + sr) * 72 + sc] = k1;
    *(bf16x8*)&Vl[0][sr * 72 + sc] = v0;
    *(bf16x8*)&Vl[0][(32 + sr) * 72 + sc] = v1;
    if (tid < 64) Ml[0][tid] = mask[b * 2048 + tid] * LOG2E;
  }
  __syncthreads();

  int cur = 0;
  for (int t = 0; t < 32; ++t) {
    // T14: issue next tile's global loads before compute
    bf16x8 ks0, ks1, vs0, vs1;
    float mn = 0.f;
    if (t < 31) {
      const int n0 = (t + 1) * 64;
      ks0 = *(const bf16x8*)(Kb + bhoff + (size_t)(n0 + sr) * 64 + sc);
      ks1 = *(const bf16x8*)(Kb + bhoff + (size_t)(n0 + 32 + sr) * 64 + sc);
      vs0 = *(const bf16x8*)(Vt + bhoff + (size_t)sr * 2048 + n0 + sc);
      vs1 = *(const bf16x8*)(Vt + bhoff + (size_t)(32 + sr) * 2048 + n0 + sc);
      if (tid < 64) mn = mask[b * 2048 + n0 + tid] * LOG2E;
    }

    // ---- scores (4 subtiles of 16 keys, K=64 via 2 mfma each)
    f32x4 s[4];
#pragma unroll
    for (int kt = 0; kt < 4; ++kt) {
      const bf16x8 ka0 = *(const bf16x8*)&Kl[cur][(kt * 16 + lq) * 72 + lg * 8];
      const bf16x8 ka1 = *(const bf16x8*)&Kl[cur][(kt * 16 + lq) * 72 + 32 + lg * 8];
      f32x4 ts = {};
      ts = __builtin_amdgcn_mfma_f32_16x16x32_bf16(ka0, qf0, ts, 0, 0, 0);
      ts = __builtin_amdgcn_mfma_f32_16x16x32_bf16(ka1, qf1, ts, 0, 0, 0);
      const f32x4 mv = *(const f32x4*)&Ml[cur][kt * 16 + lg * 4];
      s[kt] = ts + mv;
    }

    // ---- tile max (tree) + wave reduce over the 4-lane groups sharing q
    float a[4];
#pragma unroll
    for (int kt = 0; kt < 4; ++kt)
      a[kt] = fmaxf(fmaxf(s[kt][0], s[kt][1]), fmaxf(s[kt][2], s[kt][3]));
    float pm = fmaxf(fmaxf(a[0], a[1]), fmaxf(a[2], a[3]));
    pm = fmaxf(pm, __shfl_xor(pm, 16));
    pm = fmaxf(pm, __shfl_xor(pm, 32));

    // T13 defer-max: skip rescale when no lane's max grew by > 8 (exp2 <= 256)
    const bool need = !__all(pm <= m_run + 8.f);
    float mref = m_run, resc = 1.f;
    if (need) {
      mref = fmaxf(m_run, pm);
      resc = exp2f(m_run - mref);
    }

    // ---- exp + row-sum (tree) + bf16 P
    bf16x4 pf[4];
    float ps[4];
#pragma unroll
    for (int kt = 0; kt < 4; ++kt) {
      float p0 = exp2f(s[kt][0] - mref), p1 = exp2f(s[kt][1] - mref);
      float p2 = exp2f(s[kt][2] - mref), p3 = exp2f(s[kt][3] - mref);
      pf[kt][0] = f2bf(p0); pf[kt][1] = f2bf(p1);
      pf[kt][2] = f2bf(p2); pf[kt][3] = f2bf(p3);
      ps[kt] = (p0 + p1) + (p2 + p3);
    }
    float psum = (ps[0] + ps[1]) + (ps[2] + ps[3]);
    psum += __shfl_xor(psum, 16);
    psum += __shfl_xor(psum, 32);

    if (need) {
      l_run = l_run * resc + psum;
      m_run = mref;
#pragma unroll
      for (int dt = 0; dt < 4; ++dt) {
        acc[dt][0] *= resc; acc[dt][1] *= resc;
        acc[dt][2] *= resc; acc[dt][3] *= resc;
      }
    } else {
      l_run += psum;
    }

    // ---- PV at K=32, key-permuted fragments
    const bf16x8 pb0 = __builtin_shufflevector(pf[0], pf[1], 0, 1, 2, 3, 4, 5, 6, 7);
    const bf16x8 pb1 = __builtin_shufflevector(pf[2], pf[3], 0, 1, 2, 3, 4, 5, 6, 7);
#pragma unroll
    for (int dt = 0; dt < 4; ++dt) {
      const short* vr = &Vl[cur][(dt * 16 + lq) * 72];
      const bf16x4 a0 = *(const bf16x4*)(vr + 4 * lg);
      const bf16x4 a1 = *(const bf16x4*)(vr + 16 + 4 * lg);
      const bf16x4 a2 = *(const bf16x4*)(vr + 32 + 4 * lg);
      const bf16x4 a3 = *(const bf16x4*)(vr + 48 + 4 * lg);
      const bf16x8 av0 = __builtin_shufflevector(a0, a1, 0, 1, 2, 3, 4, 5, 6, 7);
      const bf16x8 av1 = __builtin_shufflevector(a2, a3, 0, 1, 2, 3, 4, 5, 6, 7);
      acc[dt] = __builtin_amdgcn_mfma_f32_16x16x32_bf16(av0, pb0, acc[dt], 0, 0, 0);
      acc[dt] = __builtin_amdgcn_mfma_f32_16x16x32_bf16(av1, pb1, acc[dt], 0, 0, 0);
    }

    // ---- write next tile into the other buffer, single barrier
    if (t < 31) {
      const int nb = cur ^ 1;
      *(bf16x8*)&Kl[nb][sr * 72 + sc] = ks0;
      *(bf16x8*)&Kl[nb][(32 + sr) * 72 + sc] = ks1;
      *(bf16x8*)&Vl[nb][sr * 72 + sc] = vs0;
      *(bf16x8*)&Vl[nb][(32 + sr) * 72 + sc] = vs1;
      if (tid < 64) Ml[nb][tid] = mn;
      __syncthreads();
      cur = nb;
    }
  }

  const float inv = gscale[h] / l_run;
#pragma unroll
  for (int dt = 0; dt < 4; ++dt) {
    bf16x4 o;
#pragma unroll
    for (int r = 0; r < 4; ++r) o[r] = f2bf(acc[dt][r] * inv);
    *(bf16x4*)&ctx[(size_t)(b * 2048 + qrow) * 1024 + h * 64 + dt * 16 + lg * 4] = o;
  }
}

// ---------------------------------------------------------------- launch
extern "C" void kernel_launch(void* const* d_in, const int* in_sizes, int n_in,
                              void* d_out, int out_size, void* d_ws, size_t ws_size,
                              hipStream_t stream) {
  (void)in_sizes; (void)n_in; (void)out_size; (void)ws_size;
  const float* x    = (const float*)d_in[0];
  const float* mask = (const float*)d_in[1];
  const float* Wq   = (const float*)d_in[2];
  const float* Wk   = (const float*)d_in[3];
  const float* Wv   = (const float*)d_in[4];
  const float* Wo   = (const float*)d_in[5];
  const float* gate = (const float*)d_in[6];
  float* out = (float*)d_out;

  char* ws = (char*)d_ws;
  const size_t MB = 1024 * 1024;
  float* scale = (float*)ws;
  short* Xb  = (short*)(ws + 256);             // 8 MB  [4096][1024]
  short* Wt3 = (short*)(ws + 256 + 8 * MB);    // 6 MB  [3072][1024] stacked Q,K,V (transposed)
  short* Wot = (short*)(ws + 256 + 14 * MB);   // 2 MB  [1024][1024]
  short* Qb  = (short*)(ws + 256 + 16 * MB);   // 8 MB  [B,H,S,D] pre-scaled
  short* Kb  = (short*)(ws + 256 + 24 * MB);   // 8 MB  [B,H,S,D]
  short* Vt  = (short*)(ws + 256 + 32 * MB);   // 8 MB  [B,H,D,S]
  short* ctx = (short*)(ws + 256 + 40 * MB);   // 8 MB  [4096][1024] gate-scaled

  gate_kernel<<<1, 64, 0, stream>>>(gate, scale);
  cvt_x_kernel<<<2048, 256, 0, stream>>>(x, Xb, 4194304 / 4);
  transpose_conv_kernel<<<dim3(32, 2, 16), 256, 0, stream>>>(Wq, Wt3, 1024, 64, 65536, 65536);
  transpose_conv_kernel<<<dim3(32, 2, 16), 256, 0, stream>>>(Wk, Wt3 + 1048576, 1024, 64, 65536, 65536);
  transpose_conv_kernel<<<dim3(32, 2, 16), 256, 0, stream>>>(Wv, Wt3 + 2097152, 1024, 64, 65536, 65536);
  transpose_conv_kernel<<<dim3(32, 32, 1), 256, 0, stream>>>(Wo, Wot, 1024, 1024, 0, 0);
  gemm_qkv_kernel<<<dim3(32, 24), 256, 0, stream>>>(Xb, Wt3, Qb, Kb, Vt);
  attn_kernel<<<dim3(32, 32), 256, 0, stream>>>(Qb, Kb, Vt, mask, scale, ctx);
  gemm_out_kernel<<<dim3(32, 8), 256, 0, stream>>>(ctx, Wot, out);
}

// Round 4
// 198.379 us; speedup vs baseline: 1.4234x; 1.1817x over previous
//
#include <hip/hip_runtime.h>
#include <hip/hip_bf16.h>

typedef short bf16x4 __attribute__((ext_vector_type(4)));
typedef short bf16x8 __attribute__((ext_vector_type(8)));
typedef float f32x4  __attribute__((ext_vector_type(4)));

#define LOG2E 1.4426950408889634f
#define QSCALE (0.125f * LOG2E)   // 1/sqrt(64) * log2(e), folded into Q

__device__ __forceinline__ short f2bf(float x) {
  union { __hip_bfloat16 h; short s; } u;
  u.h = __float2bfloat16(x);
  return u.s;
}

__device__ __forceinline__ float fast_exp2(float x) {
#if __has_builtin(__builtin_amdgcn_exp2f)
  return __builtin_amdgcn_exp2f(x);
#else
  return exp2f(x);
#endif
}

// global -> LDS direct copy, 16B per lane. LDS dest = uniform base + lane*16;
// global source address is PER-LANE (enables pre-swizzled source).
__device__ __forceinline__ void load16_lds(const void* g, void* l) {
#if __has_builtin(__builtin_amdgcn_global_load_lds)
  __builtin_amdgcn_global_load_lds(
      (const __attribute__((address_space(1))) unsigned int*)g,
      (__attribute__((address_space(3))) unsigned int*)l, 16, 0, 0);
#else
  const int lane = threadIdx.x & 63;
  *(bf16x8*)((char*)l + lane * 16) = *(const bf16x8*)((const char*)g + lane * 16);
#endif
}

// ---------------------------------------------------------------- gate scale
__global__ void gate_kernel(const float* __restrict__ gate, float* __restrict__ scale) {
  const int h = threadIdx.x;
  if (h >= 16) return;
  const float g = gate[h];
  const float eff = (g >= 1e-4f) ? g : 0.f;
  int active = 0;
  for (int j = 0; j < 16; ++j) active += (gate[j] > 1e-4f) ? 1 : 0;
  const float denom = fmaxf(1.f, (float)active / 16.f);
  scale[h] = eff / denom;
}

// ---------------------------------------------------------------- x -> bf16
__global__ __launch_bounds__(256)
void cvt_x_kernel(const float* __restrict__ in, short* __restrict__ out, int n4) {
  for (int i = blockIdx.x * blockDim.x + threadIdx.x; i < n4; i += gridDim.x * blockDim.x) {
    const float4 v = ((const float4*)in)[i];
    bf16x4 o;
    o[0] = f2bf(v.x); o[1] = f2bf(v.y); o[2] = f2bf(v.z); o[3] = f2bf(v.w);
    ((bf16x4*)out)[i] = o;
  }
}

// ---------------------- all 4 weight transposes, one dispatch (grid 4096)
__global__ __launch_bounds__(256)
void trans_all_kernel(const float* __restrict__ Wq, const float* __restrict__ Wk,
                      const float* __restrict__ Wv, const float* __restrict__ Wo,
                      short* __restrict__ Wt3, short* __restrict__ Wot) {
  __shared__ float t[32][33];
  const int f = blockIdx.x;
  const float* in;
  short* out;
  int R, C, r0, c0;
  if (f < 3072) {
    const int which = f >> 10;           // 0=Wq 1=Wk 2=Wv
    const int rem = f & 1023;
    const int z = rem >> 6;              // head
    const int xy = rem & 63;             // 32 x-tiles * 2 y-tiles
    in = (which == 0 ? Wq : which == 1 ? Wk : Wv) + (size_t)z * 65536;
    out = Wt3 + (size_t)which * 1048576 + (size_t)z * 65536;
    R = 1024; C = 64; r0 = (xy >> 1) * 32; c0 = (xy & 1) * 32;
  } else {
    const int rem = f - 3072;
    in = Wo; out = Wot;
    R = 1024; C = 1024; r0 = (rem >> 5) * 32; c0 = (rem & 31) * 32;
  }
  const int tr = threadIdx.x >> 5, tc = threadIdx.x & 31;
#pragma unroll
  for (int p = 0; p < 4; ++p)
    t[tr + p * 8][tc] = in[(size_t)(r0 + tr + p * 8) * C + c0 + tc];
  __syncthreads();
#pragma unroll
  for (int p = 0; p < 4; ++p)
    out[(size_t)(c0 + tr + p * 8) * R + r0 + tc] = f2bf(t[tc][tr + p * 8]);
}

// ---------------------------------------------------------------- fused QKV GEMM
// C[4096][3072] = Xb[4096][1024] * Wt3[3072][1024]^T; 128x128 tile, 4 waves.
__global__ __launch_bounds__(256)
void gemm_qkv_kernel(const short* __restrict__ A, const short* __restrict__ Bt,
                     short* __restrict__ Qb, short* __restrict__ Kb,
                     short* __restrict__ Vt) {
  __shared__ short Al[128 * 32];
  __shared__ short Bl[128 * 32];
  const int tid = threadIdx.x;
  const int w = tid >> 6, lane = tid & 63;
  const int lq = lane & 15, lg = lane >> 4;
  const int m0 = blockIdx.x * 128, n0 = blockIdx.y * 128;
  const int which = n0 >> 10;  // 0=Q 1=K 2=V
  const int wr = (w >> 1) * 64, wc = (w & 1) * 64;

  f32x4 acc[4][4] = {};
  const int grow = lane >> 2;
  const int gcol = (lane & 3) * 8;

  for (int k0 = 0; k0 < 1024; k0 += 32) {
#pragma unroll
    for (int c = 0; c < 2; ++c) {
      const int chunk = (w << 1) | c;
      const int row = chunk * 16 + grow;
      load16_lds(A + (size_t)(m0 + row) * 1024 + k0 + gcol, &Al[chunk * 512]);
      load16_lds(Bt + (size_t)(n0 + row) * 1024 + k0 + gcol, &Bl[chunk * 512]);
    }
    __syncthreads();
    bf16x8 af[4], bfr[4];
#pragma unroll
    for (int i = 0; i < 4; ++i)
      af[i] = *(const bf16x8*)&Al[(wr + i * 16 + lq) * 32 + lg * 8];
#pragma unroll
    for (int j = 0; j < 4; ++j)
      bfr[j] = *(const bf16x8*)&Bl[(wc + j * 16 + lq) * 32 + lg * 8];
#pragma unroll
    for (int i = 0; i < 4; ++i)
#pragma unroll
      for (int j = 0; j < 4; ++j)
        acc[i][j] = __builtin_amdgcn_mfma_f32_16x16x32_bf16(af[i], bfr[j], acc[i][j], 0, 0, 0);
    __syncthreads();
  }

  if (which < 2) {
    short* Out = which ? Kb : Qb;
    const float sc = which ? 1.f : QSCALE;
#pragma unroll
    for (int i = 0; i < 4; ++i)
#pragma unroll
      for (int j = 0; j < 4; ++j) {
        const int nn = (n0 + wc + j * 16 + lq) & 1023;
        const int h = nn >> 6, d = nn & 63;
#pragma unroll
        for (int r = 0; r < 4; ++r) {
          const int m = m0 + wr + i * 16 + lg * 4 + r;
          const int b = m >> 11, s = m & 2047;
          Out[(size_t)((b * 16 + h) * 2048 + s) * 64 + d] = f2bf(acc[i][j][r] * sc);
        }
      }
  } else {
#pragma unroll
    for (int i = 0; i < 4; ++i) {
      const int mb = m0 + wr + i * 16 + lg * 4;
      const int b = mb >> 11, s = mb & 2047;
#pragma unroll
      for (int j = 0; j < 4; ++j) {
        const int nn = (n0 + wc + j * 16 + lq) & 1023;
        const int h = nn >> 6, d = nn & 63;
        bf16x4 o;
#pragma unroll
        for (int r = 0; r < 4; ++r) o[r] = f2bf(acc[i][j][r]);
        *(bf16x4*)&Vt[(size_t)((b * 16 + h) * 64 + d) * 2048 + s] = o;
      }
    }
  }
}

// ---------------------------------------------------------------- out-proj GEMM
__global__ __launch_bounds__(256)
void gemm_out_kernel(const short* __restrict__ A, const short* __restrict__ Bt,
                     float* __restrict__ Out) {
  __shared__ short Al[128 * 32];
  __shared__ short Bl[128 * 32];
  const int tid = threadIdx.x;
  const int w = tid >> 6, lane = tid & 63;
  const int lq = lane & 15, lg = lane >> 4;
  const int m0 = blockIdx.x * 128, n0 = blockIdx.y * 128;
  const int wr = (w >> 1) * 64, wc = (w & 1) * 64;

  f32x4 acc[4][4] = {};
  const int grow = lane >> 2;
  const int gcol = (lane & 3) * 8;

  for (int k0 = 0; k0 < 1024; k0 += 32) {
#pragma unroll
    for (int c = 0; c < 2; ++c) {
      const int chunk = (w << 1) | c;
      const int row = chunk * 16 + grow;
      load16_lds(A + (size_t)(m0 + row) * 1024 + k0 + gcol, &Al[chunk * 512]);
      load16_lds(Bt + (size_t)(n0 + row) * 1024 + k0 + gcol, &Bl[chunk * 512]);
    }
    __syncthreads();
    bf16x8 af[4], bfr[4];
#pragma unroll
    for (int i = 0; i < 4; ++i)
      af[i] = *(const bf16x8*)&Al[(wr + i * 16 + lq) * 32 + lg * 8];
#pragma unroll
    for (int j = 0; j < 4; ++j)
      bfr[j] = *(const bf16x8*)&Bl[(wc + j * 16 + lq) * 32 + lg * 8];
#pragma unroll
    for (int i = 0; i < 4; ++i)
#pragma unroll
      for (int j = 0; j < 4; ++j)
        acc[i][j] = __builtin_amdgcn_mfma_f32_16x16x32_bf16(af[i], bfr[j], acc[i][j], 0, 0, 0);
    __syncthreads();
  }

#pragma unroll
  for (int i = 0; i < 4; ++i)
#pragma unroll
    for (int r = 0; r < 4; ++r) {
      const int m = m0 + wr + i * 16 + lg * 4 + r;
      float* orow = Out + (size_t)m * 1024 + n0 + wc;
#pragma unroll
      for (int j = 0; j < 4; ++j) orow[j * 16 + lq] = acc[i][j][r];
    }
}

// ---------------------------------------------------------------- flash attention
// KEY-SPLIT: grid x=q-tile(64 rows), y=b*16+h. 4 waves; per 128-key tile each
// wave owns 32 keys x ALL 64 q. Fixed-reference softmax (no max tracking:
// scores data-bounded, shift-invariant) makes wave partials additive; O/l
// merged once at the end via LDS. Staging via global_load_lds with XOR-swizzled
// per-lane SOURCE (linear LDS dest); reads apply the same XOR -> conflict-free.
// K LDS: [128 key][64 d], byte = key*128 + ((d*2) ^ ((key&7)<<4))
// V LDS: [64 d][128 key], byte = d*256 + ((k*2) ^ ((d&7)<<4))
__global__ __launch_bounds__(256, 2)
void attn_kernel(const short* __restrict__ Qb, const short* __restrict__ Kb,
                 const short* __restrict__ Vt, const float* __restrict__ mask,
                 const float* __restrict__ gscale, short* __restrict__ ctx) {
  __shared__ __align__(16) char lds[66560];
  // [0,16K) Kl0 | [16K,32K) Kl1 | [32K,48K) Vl0 | [48K,64K) Vl1
  // merge phase reuses [0,64K) as float[4][64 q][64 d] (swizzled); Lbuf @64K.

  const int tid = threadIdx.x;
  const int w = tid >> 6, lane = tid & 63;
  const int lq = lane & 15, lg = lane >> 4;
  const int bh = blockIdx.y, b = bh >> 4, h = bh & 15;
  const int q0 = blockIdx.x * 64;
  const size_t bhoff = (size_t)bh * 2048 * 64;

  // Q B-frags for all 64 q: qf[qt][half] = Q[q0+qt*16+lq][half*32 + lg*8 ..+7]
  bf16x8 qf[4][2];
#pragma unroll
  for (int qt = 0; qt < 4; ++qt) {
    const short* qp = Qb + bhoff + (size_t)(q0 + qt * 16 + lq) * 64 + lg * 8;
    qf[qt][0] = *(const bf16x8*)qp;
    qf[qt][1] = *(const bf16x8*)(qp + 32);
  }

  // staging lane constants (pre-swizzled global source offsets)
  const int koffs = (lane >> 3) * 128 + (((lane & 7) * 16) ^ ((lane >> 3) << 4));
  const int vrowc = lane >> 4;
  const int vs_e = ((lane & 15) * 16) ^ (vrowc << 4);
  const int vs_o = ((lane & 15) * 16) ^ ((vrowc + 4) << 4);
  const char* KbB = (const char*)(Kb + bhoff);
  const char* VtB = (const char*)(Vt + bhoff);

  // read-side constants
  const int sw = (lq & 7) << 4;
  const int kcol0 = (lg * 16) ^ sw, kcol1 = (64 + lg * 16) ^ sw;
  const int vcol0 = (w * 64 + lg * 8) ^ sw, vcol1 = (w * 64 + 32 + lg * 8) ^ sw;
  const float* maskp = mask + b * 2048;

  f32x4 acc[4][4] = {};  // [dt][qt]: O_partial[d=dt*16+lg*4+r][q=qt*16+lq]
  f32x4 lacc[4] = {};    // [qt] partial sum of p (components = distinct keys)

#define STAGE(T, P)                                                              \
  {                                                                              \
    char* kd = lds + (P)*16384 + w * 4096;                                       \
    const char* ks = KbB + (size_t)((T)*128 + w * 32) * 128 + koffs;             \
    char* vd = lds + 32768 + (P)*16384 + w * 4096;                               \
    const char* vsb = VtB + (size_t)(w * 16 + vrowc) * 4096 + (T)*256;           \
    load16_lds(ks, kd);                                                          \
    load16_lds(ks + 1024, kd + 1024);                                            \
    load16_lds(ks + 2048, kd + 2048);                                            \
    load16_lds(ks + 3072, kd + 3072);                                            \
    load16_lds(vsb + vs_e, vd);                                                  \
    load16_lds(vsb + 16384 + vs_o, vd + 1024);                                   \
    load16_lds(vsb + 32768 + vs_e, vd + 2048);                                   \
    load16_lds(vsb + 49152 + vs_o, vd + 3072);                                   \
  }

  STAGE(0, 0);
  __syncthreads();

  for (int t = 0; t < 16; ++t) {
    const int cur = t & 1;
    // mask first (so stage loads issued after don't get drained by its wait)
    const f32x4 mk0 = *(const f32x4*)(maskp + t * 128 + w * 32 + lg * 4);
    const f32x4 mk1 = *(const f32x4*)(maskp + t * 128 + w * 32 + 16 + lg * 4);
    if (t < 15) STAGE(t + 1, cur ^ 1);

    // ---- scores: s[kt][qt], key = t*128 + w*32 + kt*16 + lg*4 + r, q = qt*16+lq
    const char* Kc = lds + cur * 16384 + (w * 32 + lq) * 128;
    f32x4 s[2][4];
#pragma unroll
    for (int kt = 0; kt < 2; ++kt) {
      const bf16x8 ka0 = *(const bf16x8*)(Kc + kt * 2048 + kcol0);
      const bf16x8 ka1 = *(const bf16x8*)(Kc + kt * 2048 + kcol1);
#pragma unroll
      for (int qt = 0; qt < 4; ++qt) {
        f32x4 ts = {};
        ts = __builtin_amdgcn_mfma_f32_16x16x32_bf16(ka0, qf[qt][0], ts, 0, 0, 0);
        ts = __builtin_amdgcn_mfma_f32_16x16x32_bf16(ka1, qf[qt][1], ts, 0, 0, 0);
        s[kt][qt] = ts;
      }
    }

    // ---- fixed-ref softmax: p = exp2(s + m*log2e)
    bf16x4 pf[2][4];
#pragma unroll
    for (int kt = 0; kt < 2; ++kt) {
      const f32x4 mkv = kt ? mk1 : mk0;
#pragma unroll
      for (int qt = 0; qt < 4; ++qt) {
        const float p0 = fast_exp2(fmaf(mkv[0], LOG2E, s[kt][qt][0]));
        const float p1 = fast_exp2(fmaf(mkv[1], LOG2E, s[kt][qt][1]));
        const float p2 = fast_exp2(fmaf(mkv[2], LOG2E, s[kt][qt][2]));
        const float p3 = fast_exp2(fmaf(mkv[3], LOG2E, s[kt][qt][3]));
        pf[kt][qt][0] = f2bf(p0); pf[kt][qt][1] = f2bf(p1);
        pf[kt][qt][2] = f2bf(p2); pf[kt][qt][3] = f2bf(p3);
        const f32x4 pv = {p0, p1, p2, p3};
        lacc[qt] += pv;
      }
    }

    // ---- PV at K=32 (32-key contraction), key-permuted fragments
    bf16x8 pb[4];
#pragma unroll
    for (int qt = 0; qt < 4; ++qt)
      pb[qt] = __builtin_shufflevector(pf[0][qt], pf[1][qt], 0, 1, 2, 3, 4, 5, 6, 7);
#pragma unroll
    for (int dt = 0; dt < 4; ++dt) {
      const char* Vrow = lds + 32768 + cur * 16384 + (dt * 16 + lq) * 256;
      const bf16x4 v0 = *(const bf16x4*)(Vrow + vcol0);
      const bf16x4 v1 = *(const bf16x4*)(Vrow + vcol1);
      const bf16x8 av = __builtin_shufflevector(v0, v1, 0, 1, 2, 3, 4, 5, 6, 7);
#pragma unroll
      for (int qt = 0; qt < 4; ++qt)
        acc[dt][qt] = __builtin_amdgcn_mfma_f32_16x16x32_bf16(av, pb[qt], acc[dt][qt], 0, 0, 0);
    }

    __syncthreads();  // drains next-tile stage; all waves done with cur
  }
#undef STAGE

  // ---- merge: partials -> LDS float[w][q][d] (row 256B, XOR-swizzled)
#pragma unroll
  for (int dt = 0; dt < 4; ++dt)
#pragma unroll
    for (int qt = 0; qt < 4; ++qt)
      *(f32x4*)(lds + w * 16384 + (qt * 16 + lq) * 256 + ((dt * 64 + lg * 16) ^ sw)) =
          acc[dt][qt];

  // per-wave l partials: reduce with ALL lanes active, guard only the store
  float* Lb = (float*)(lds + 65536);
#pragma unroll
  for (int qt = 0; qt < 4; ++qt) {
    float lt = (lacc[qt][0] + lacc[qt][1]) + (lacc[qt][2] + lacc[qt][3]);
    lt += __shfl_xor(lt, 16);
    lt += __shfl_xor(lt, 32);
    if (lg == 0) Lb[w * 64 + qt * 16 + lq] = lt;
  }
  __syncthreads();

  // this wave finalizes q-rows w*16 + lq
  const float lsum = Lb[w * 16 + lq] + Lb[64 + w * 16 + lq] +
                     Lb[128 + w * 16 + lq] + Lb[192 + w * 16 + lq];
  const float osc = gscale[h] / lsum;
  const int qabs = q0 + w * 16 + lq;
#pragma unroll
  for (int dt = 0; dt < 4; ++dt) {
    const int dby = (dt * 64 + lg * 16) ^ sw;
    f32x4 o = *(const f32x4*)(lds + (w * 16 + lq) * 256 + dby);
    o += *(const f32x4*)(lds + 16384 + (w * 16 + lq) * 256 + dby);
    o += *(const f32x4*)(lds + 32768 + (w * 16 + lq) * 256 + dby);
    o += *(const f32x4*)(lds + 49152 + (w * 16 + lq) * 256 + dby);
    bf16x4 ob;
#pragma unroll
    for (int r = 0; r < 4; ++r) ob[r] = f2bf(o[r] * osc);
    *(bf16x4*)&ctx[(size_t)(b * 2048 + qabs) * 1024 + h * 64 + dt * 16 + lg * 4] = ob;
  }
}

// ---------------------------------------------------------------- launch
extern "C" void kernel_launch(void* const* d_in, const int* in_sizes, int n_in,
                              void* d_out, int out_size, void* d_ws, size_t ws_size,
                              hipStream_t stream) {
  (void)in_sizes; (void)n_in; (void)out_size; (void)ws_size;
  const float* x    = (const float*)d_in[0];
  const float* mask = (const float*)d_in[1];
  const float* Wq   = (const float*)d_in[2];
  const float* Wk   = (const float*)d_in[3];
  const float* Wv   = (const float*)d_in[4];
  const float* Wo   = (const float*)d_in[5];
  const float* gate = (const float*)d_in[6];
  float* out = (float*)d_out;

  char* ws = (char*)d_ws;
  const size_t MB = 1024 * 1024;
  float* scale = (float*)ws;
  short* Xb  = (short*)(ws + 256);             // 8 MB  [4096][1024]
  short* Wt3 = (short*)(ws + 256 + 8 * MB);    // 6 MB  stacked Q,K,V transposed
  short* Wot = (short*)(ws + 256 + 14 * MB);   // 2 MB  [1024][1024]
  short* Qb  = (short*)(ws + 256 + 16 * MB);   // 8 MB  [B,H,S,D] pre-scaled
  short* Kb  = (short*)(ws + 256 + 24 * MB);   // 8 MB  [B,H,S,D]
  short* Vt  = (short*)(ws + 256 + 32 * MB);   // 8 MB  [B,H,D,S]
  short* ctx = (short*)(ws + 256 + 40 * MB);   // 8 MB  [4096][1024] gate-scaled

  gate_kernel<<<1, 64, 0, stream>>>(gate, scale);
  cvt_x_kernel<<<2048, 256, 0, stream>>>(x, Xb, 4194304 / 4);
  trans_all_kernel<<<4096, 256, 0, stream>>>(Wq, Wk, Wv, Wo, Wt3, Wot);
  gemm_qkv_kernel<<<dim3(32, 24), 256, 0, stream>>>(Xb, Wt3, Qb, Kb, Vt);
  attn_kernel<<<dim3(32, 32), 256, 0, stream>>>(Qb, Kb, Vt, mask, scale, ctx);
  gemm_out_kernel<<<dim3(32, 8), 256, 0, stream>>>(ctx, Wot, out);
}